// Round 9
// baseline (437.939 us; speedup 1.0000x reference)
//
#include <hip/hip_runtime.h>

#define D 64
#define NPB 128              // nodes per bucket (dstLocal: 7 bits)
#define NPB_SHIFT 7
#define CAP 4096             // slot capacity per bucket (mean 1534 at E=1.2M,B=782)

// round-to-nearest-even fp32 -> bf16
__device__ inline unsigned f2bf(float f) {
    unsigned u = __float_as_uint(f);
    return (u + 0x7FFFu + ((u >> 16) & 1u)) >> 16;
}

// ---------------------------------------------------------------------------
// zero helper (ws is poisoned 0xAA every launch)
// ---------------------------------------------------------------------------
__global__ void zero_i_kernel(int* __restrict__ p, int n) {
    int i = blockIdx.x * blockDim.x + threadIdx.x;
    if (i < n) p[i] = 0;
}
__global__ void zero_f4_kernel(float4* __restrict__ p, int n4) {
    int i = blockIdx.x * blockDim.x + threadIdx.x;
    if (i < n4) p[i] = make_float4(0.f, 0.f, 0.f, 0.f);
}

// ---------------------------------------------------------------------------
// slotted bucket fill: no hist/scan needed. Per edge: one independent
// global atomic (782 counters, ~1534 hits each) + one scattered 8B store
// into the bucket's private CAP-entry region. Pure TLP, no barriers
// (r8 post-mortem: the 3-phase scatter was barrier/LDS-chain serialized
// at VALU 1.6% regardless of occupancy).
// Packing: x = src | dstLocal<<20 (needs N < 2^20), y = w bits.
// ---------------------------------------------------------------------------
__global__ __launch_bounds__(256) void fill_bucket_kernel(
        const int* __restrict__ src, const int* __restrict__ dst,
        const float* __restrict__ w, int* __restrict__ cursor,
        int2* __restrict__ adjB, int E) {
    int i = blockIdx.x * blockDim.x + threadIdx.x;
    if (i >= E) return;
    int td = dst[i];
    int b = td >> NPB_SHIFT;
    int pos = atomicAdd(&cursor[b], 1);
    if (pos < CAP)
        adjB[(size_t)b * CAP + pos] =
            make_int2(src[i] | ((td & (NPB - 1)) << 20), __float_as_int(w[i]));
}

// ---------------------------------------------------------------------------
// single-pass register counting sort per bucket: block loads its <=4096
// entries into registers (16/thread, coalesced, 16 independent loads in
// flight), gets the per-node rank FROM the counting LDS atomic, wave-0
// shfl-scan of cnt[128] (no barrier ladder), then writes node-grouped adj
// once. Emits rowStart/rowEnd (bucket regions are slotted -> gaps, so an
// explicit end array instead of rowStart[n+1]).
// ---------------------------------------------------------------------------
__global__ __launch_bounds__(256) void sort_bucket_kernel(
        const int2* __restrict__ adjB, const int* __restrict__ cursor,
        int2* __restrict__ adj, int* __restrict__ rowStart,
        int* __restrict__ rowEnd, int N) {
    __shared__ int cnt[NPB];
    __shared__ int pre[NPB];
    int b = blockIdx.x;
    int base = b * CAP;
    int M = min(cursor[b], CAP);
    int t = threadIdx.x;
    if (t < NPB) cnt[t] = 0;
    __syncthreads();

    int2 a[16];
    int  rk[16];
#pragma unroll
    for (int r = 0; r < 16; ++r) {
        int idx = r * 256 + t;
        if (idx < M) {
            a[r] = adjB[base + idx];
            rk[r] = atomicAdd(&cnt[((unsigned)a[r].x) >> 20], 1);
        }
    }
    __syncthreads();

    // wave-0 exclusive scan of cnt[128] -> pre (2 elems per lane, shfl scan)
    if (t < 64) {
        int c0 = cnt[2 * t], c1 = cnt[2 * t + 1];
        int s = c0 + c1;
        int incl = s;
#pragma unroll
        for (int d = 1; d < 64; d <<= 1) {
            int v = __shfl_up(incl, d, 64);
            if (t >= d) incl += v;
        }
        int excl = incl - s;
        pre[2 * t] = excl;
        pre[2 * t + 1] = excl + c0;
    }
    __syncthreads();

#pragma unroll
    for (int r = 0; r < 16; ++r) {
        int idx = r * 256 + t;
        if (idx < M) {
            int dL = ((unsigned)a[r].x) >> 20;
            adj[base + pre[dL] + rk[r]] = make_int2(a[r].x & 0xFFFFF, a[r].y);
        }
    }
    if (t < NPB) {
        int node = b * NPB + t;
        if (node < N) {
            rowStart[node] = base + pre[t];
            rowEnd[node]   = base + pre[t] + cnt[t];
        }
    }
}

// ---------------------------------------------------------------------------
// Tiled row GEMM -> bf16 packed proj. Block = 64 rows; A transposed in LDS;
// theta in LDS; thread computes 4x4 block. __launch_bounds__(256,4) caps
// VGPR at 128 (r5: epilogue hoisting -> 252 VGPR, 9% occupancy).
// ---------------------------------------------------------------------------
__global__ __launch_bounds__(256, 4) void rowgemm_bf16_kernel(const float* __restrict__ A,
                                                              const float* __restrict__ theta,
                                                              unsigned short* __restrict__ proj16,
                                                              int N) {
    __shared__ float th[D * D];
    __shared__ float at[D][68];
    int t = threadIdx.x;
    int rowBase = blockIdx.x * 64;

#pragma unroll
    for (int i = 0; i < 4; ++i) {
        int f = t + i * 256;
        ((float4*)th)[f] = ((const float4*)theta)[f];
    }
#pragma unroll
    for (int i = 0; i < 4; ++i) {
        int f = t + i * 256;
        int row = f >> 4;
        int kv = f & 15;
        float4 v = make_float4(0.f, 0.f, 0.f, 0.f);
        if (rowBase + row < N) v = *(const float4*)&A[(size_t)(rowBase + row) * D + kv * 4];
        at[kv * 4 + 0][row] = v.x;
        at[kv * 4 + 1][row] = v.y;
        at[kv * 4 + 2][row] = v.z;
        at[kv * 4 + 3][row] = v.w;
    }
    __syncthreads();

    int c0 = (t & 15) * 4;
    int r0 = (t >> 4) * 4;
    float4 acc0 = make_float4(0.f, 0.f, 0.f, 0.f);
    float4 acc1 = acc0, acc2 = acc0, acc3 = acc0;

#pragma unroll 16
    for (int k = 0; k < D; ++k) {
        float4 bv = *(const float4*)&th[k * D + c0];
        float4 av = *(const float4*)&at[k][r0];
        acc0.x += av.x * bv.x; acc0.y += av.x * bv.y; acc0.z += av.x * bv.z; acc0.w += av.x * bv.w;
        acc1.x += av.y * bv.x; acc1.y += av.y * bv.y; acc1.z += av.y * bv.z; acc1.w += av.y * bv.w;
        acc2.x += av.z * bv.x; acc2.y += av.z * bv.y; acc2.z += av.z * bv.z; acc2.w += av.z * bv.w;
        acc3.x += av.w * bv.x; acc3.y += av.w * bv.y; acc3.z += av.w * bv.z; acc3.w += av.w * bv.w;
    }

    float4 accs[4] = {acc0, acc1, acc2, acc3};
#pragma unroll
    for (int i = 0; i < 4; ++i) {
        int r = rowBase + r0 + i;
        if (r < N) {
            unsigned lo = f2bf(accs[i].x) | (f2bf(accs[i].y) << 16);
            unsigned hi = f2bf(accs[i].z) | (f2bf(accs[i].w) << 16);
            *(uint2*)&proj16[(size_t)r * D + c0] = make_uint2(lo, hi);
        }
    }
}

// ---------------------------------------------------------------------------
// gather v3 (unchanged structure, rowEnd instead of rowStart[n+1]): one
// wave per node; each HALF-wave handles 4 edges/iter via uniform-address
// adj loads; 4 independent 256B proj row loads in flight per wave.
// ---------------------------------------------------------------------------
__global__ void gather_kernel(const int* __restrict__ rowStart, const int* __restrict__ rowEnd,
                              const int2* __restrict__ adj,
                              const unsigned* __restrict__ projU, float* __restrict__ out, int N) {
    int wid = (blockIdx.x * blockDim.x + threadIdx.x) >> 6;
    int lane = threadIdx.x & 63;
    if (wid >= N) return;
    int beg = rowStart[wid];
    int end = rowEnd[wid];
    int half = lane >> 5;
    int k = lane & 31;

    float2 acc0 = make_float2(0.f, 0.f);
    float2 acc1 = acc0, acc2 = acc0, acc3 = acc0;

    for (int it = beg; it < end; it += 8) {
        int e0 = it + 0 + half;
        int e1 = it + 2 + half;
        int e2 = it + 4 + half;
        int e3 = it + 6 + half;
        int2 a0 = adj[e0 < end ? e0 : beg];
        int2 a1 = adj[e1 < end ? e1 : beg];
        int2 a2 = adj[e2 < end ? e2 : beg];
        int2 a3 = adj[e3 < end ? e3 : beg];
        float w0 = (e0 < end) ? __int_as_float(a0.y) : 0.f;
        float w1 = (e1 < end) ? __int_as_float(a1.y) : 0.f;
        float w2 = (e2 < end) ? __int_as_float(a2.y) : 0.f;
        float w3 = (e3 < end) ? __int_as_float(a3.y) : 0.f;
        unsigned p0 = projU[(size_t)a0.x * 32 + k];
        unsigned p1 = projU[(size_t)a1.x * 32 + k];
        unsigned p2 = projU[(size_t)a2.x * 32 + k];
        unsigned p3 = projU[(size_t)a3.x * 32 + k];
        acc0.x += w0 * __uint_as_float(p0 << 16);
        acc0.y += w0 * __uint_as_float(p0 & 0xFFFF0000u);
        acc1.x += w1 * __uint_as_float(p1 << 16);
        acc1.y += w1 * __uint_as_float(p1 & 0xFFFF0000u);
        acc2.x += w2 * __uint_as_float(p2 << 16);
        acc2.y += w2 * __uint_as_float(p2 & 0xFFFF0000u);
        acc3.x += w3 * __uint_as_float(p3 << 16);
        acc3.y += w3 * __uint_as_float(p3 & 0xFFFF0000u);
    }
    float2 acc = make_float2(acc0.x + acc1.x + acc2.x + acc3.x,
                             acc0.y + acc1.y + acc2.y + acc3.y);
    acc.x += __shfl(acc.x, lane ^ 32, 64);
    acc.y += __shfl(acc.y, lane ^ 32, 64);
    if (half == 0)
        *(float2*)&out[(size_t)wid * D + 2 * k] = acc;   // 32 lanes x 8B coalesced
}

// ---------------------------------------------------------------------------
// fallback path (atomic scatter + fp32 row GEMM) if ws/shape checks fail
// ---------------------------------------------------------------------------
__global__ void scatter_kernel(const int* __restrict__ src, const int* __restrict__ dst,
                               const float* __restrict__ w, const float* __restrict__ data,
                               float* __restrict__ agg, int E) {
    int tid = blockIdx.x * blockDim.x + threadIdx.x;
    int e = tid >> 6;
    int d = tid & 63;
    if (e >= E) return;
    float val = w[e] * data[(size_t)src[e] * D + d];
    atomicAdd(&agg[(size_t)dst[e] * D + d], val);
}

__global__ __launch_bounds__(256, 4) void rowgemm_f32_kernel(const float* __restrict__ A,
                                                             const float* __restrict__ theta,
                                                             float* __restrict__ out, int N) {
    __shared__ float th[D * D];
    __shared__ float at[D][68];
    int t = threadIdx.x;
    int rowBase = blockIdx.x * 64;
#pragma unroll
    for (int i = 0; i < 4; ++i) {
        int f = t + i * 256;
        ((float4*)th)[f] = ((const float4*)theta)[f];
    }
#pragma unroll
    for (int i = 0; i < 4; ++i) {
        int f = t + i * 256;
        int row = f >> 4;
        int kv = f & 15;
        float4 v = make_float4(0.f, 0.f, 0.f, 0.f);
        if (rowBase + row < N) v = *(const float4*)&A[(size_t)(rowBase + row) * D + kv * 4];
        at[kv * 4 + 0][row] = v.x;
        at[kv * 4 + 1][row] = v.y;
        at[kv * 4 + 2][row] = v.z;
        at[kv * 4 + 3][row] = v.w;
    }
    __syncthreads();
    int c0 = (t & 15) * 4;
    int r0 = (t >> 4) * 4;
    float4 acc0 = make_float4(0.f, 0.f, 0.f, 0.f);
    float4 acc1 = acc0, acc2 = acc0, acc3 = acc0;
#pragma unroll 16
    for (int kk = 0; kk < D; ++kk) {
        float4 bv = *(const float4*)&th[kk * D + c0];
        float4 av = *(const float4*)&at[kk][r0];
        acc0.x += av.x * bv.x; acc0.y += av.x * bv.y; acc0.z += av.x * bv.z; acc0.w += av.x * bv.w;
        acc1.x += av.y * bv.x; acc1.y += av.y * bv.y; acc1.z += av.y * bv.z; acc1.w += av.y * bv.w;
        acc2.x += av.z * bv.x; acc2.y += av.z * bv.y; acc2.z += av.z * bv.z; acc2.w += av.z * bv.w;
        acc3.x += av.w * bv.x; acc3.y += av.w * bv.y; acc3.z += av.w * bv.z; acc3.w += av.w * bv.w;
    }
    float4 accs[4] = {acc0, acc1, acc2, acc3};
#pragma unroll
    for (int i = 0; i < 4; ++i) {
        int r = rowBase + r0 + i;
        if (r < N) *(float4*)&out[(size_t)r * D + c0] = accs[i];
    }
}

extern "C" void kernel_launch(void* const* d_in, const int* in_sizes, int n_in,
                              void* d_out, int out_size, void* d_ws, size_t ws_size,
                              hipStream_t stream) {
    const int*   src   = (const int*)d_in[0];
    const int*   dst   = (const int*)d_in[1];
    const float* w     = (const float*)d_in[2];
    const float* data  = (const float*)d_in[3];
    const float* theta = (const float*)d_in[4];
    const int E = in_sizes[0];
    const int N = in_sizes[3] / D;
    float* out = (float*)d_out;

    const int B = (N + NPB - 1) / NPB;

    // ws layout: proj16 (bf16) | adjB (B*CAP slotted) | adj (B*CAP slotted) |
    //            cursor[B] | rowStart[N] | rowEnd[N]
    size_t projBytes = (size_t)N * D * 2;
    size_t slotBytes = (size_t)B * CAP * 8;
    size_t need = projBytes + 2 * slotBytes + (size_t)B * 4 + (size_t)N * 8 + 256;

    // CAP must comfortably exceed the expected max bucket fill (~E/B + 6 sigma)
    long long meanFill = (B > 0) ? (long long)E / B : 0;
    bool capOk = meanFill + 6 * (long long)(sqrt((double)(meanFill ? meanFill : 1))) < CAP;

    if (ws_size >= need && N < (1 << 20) && capOk) {
        unsigned short* proj16 = (unsigned short*)d_ws;
        int2* adjB     = (int2*)((char*)d_ws + projBytes);
        int2* adj      = (int2*)((char*)d_ws + projBytes + slotBytes);
        int*  cursor   = (int*)((char*)d_ws + projBytes + 2 * slotBytes);
        int*  rowStart = cursor + B;
        int*  rowEnd   = rowStart + N;

        zero_i_kernel<<<(B + 255) / 256, 256, 0, stream>>>(cursor, B);
        fill_bucket_kernel<<<(E + 255) / 256, 256, 0, stream>>>(src, dst, w, cursor, adjB, E);
        sort_bucket_kernel<<<B, 256, 0, stream>>>(adjB, cursor, adj, rowStart, rowEnd, N);
        rowgemm_bf16_kernel<<<(N + 63) / 64, 256, 0, stream>>>(data, theta, proj16, N);
        gather_kernel<<<(N + 3) / 4, 256, 0, stream>>>(rowStart, rowEnd, adj,
                                                       (const unsigned*)proj16, out, N);
    } else {
        float* agg = (float*)d_ws;
        int n4 = (N * D) / 4;
        zero_f4_kernel<<<(n4 + 255) / 256, 256, 0, stream>>>((float4*)agg, n4);
        long long total = (long long)E * D;
        scatter_kernel<<<(int)((total + 255) / 256), 256, 0, stream>>>(src, dst, w, data, agg, E);
        rowgemm_f32_kernel<<<(N + 63) / 64, 256, 0, stream>>>(agg, theta, out, N);
    }
}

// Round 10
// 215.352 us; speedup vs baseline: 2.0336x; 2.0336x over previous
//
#include <hip/hip_runtime.h>

#define D 64
#define NPB 128              // nodes per bucket (dstLocal: 7 bits)
#define NPB_SHIFT 7
#define SH 8                 // cursor shards per bucket (XCD-aligned via blockIdx&7)
#define CSUB 512             // capacity per shard (mean fill ~192 at E=1.2M,B=782: +23 sigma)
#define CAP (SH * CSUB)      // 4096 slots per bucket

// round-to-nearest-even fp32 -> bf16
__device__ inline unsigned f2bf(float f) {
    unsigned u = __float_as_uint(f);
    return (u + 0x7FFFu + ((u >> 16) & 1u)) >> 16;
}

// ---------------------------------------------------------------------------
// zero helpers (ws is poisoned 0xAA every launch)
// ---------------------------------------------------------------------------
__global__ void zero_i_kernel(int* __restrict__ p, int n) {
    int i = blockIdx.x * blockDim.x + threadIdx.x;
    if (i < n) p[i] = 0;
}
__global__ void zero_f4_kernel(float4* __restrict__ p, int n4) {
    int i = blockIdx.x * blockDim.x + threadIdx.x;
    if (i < n4) p[i] = make_float4(0.f, 0.f, 0.f, 0.f);
}

// ---------------------------------------------------------------------------
// sharded slotted fill (r9 post-mortem: 782 counters -> 1534-deep serial
// atomic chains = 285us). Shard cursor 8x by blockIdx&7: chains drop to
// ~192, and since blocks map round-robin to XCDs, each 4KB sub-region is
// written by ONE XCD -> its L2 merges the 8B stores before writeback.
// Packing: x = src | dstLocal<<20 (needs N < 2^20), y = w bits.
// ---------------------------------------------------------------------------
__global__ __launch_bounds__(256) void fill_bucket_kernel(
        const int* __restrict__ src, const int* __restrict__ dst,
        const float* __restrict__ w, int* __restrict__ cursor,
        int2* __restrict__ adjB, int E) {
    int i = blockIdx.x * blockDim.x + threadIdx.x;
    if (i >= E) return;
    int s = blockIdx.x & (SH - 1);
    int td = dst[i];
    int b = td >> NPB_SHIFT;
    int pos = atomicAdd(&cursor[b * SH + s], 1);
    if (pos < CSUB)
        adjB[(size_t)b * CAP + s * CSUB + pos] =
            make_int2(src[i] | ((td & (NPB - 1)) << 20), __float_as_int(w[i]));
}

// ---------------------------------------------------------------------------
// single-pass register counting sort per bucket (r9 structure, adapted to
// 8 sharded segments). 256 threads x 16 regs = 4096 slots; register slot r
// covers exactly half of segment r>>1 (p = (r&1)*256 + t -> static valid
// check vs ms[r>>1]). Rank comes from the counting LDS atomic; wave-0
// shfl-scan of cnt[128]; one compacted node-grouped write + rowStart/End.
// ---------------------------------------------------------------------------
__global__ __launch_bounds__(256) void sort_bucket_kernel(
        const int2* __restrict__ adjB, const int* __restrict__ cursor,
        int2* __restrict__ adj, int* __restrict__ rowStart,
        int* __restrict__ rowEnd, int N) {
    __shared__ int cnt[NPB];
    __shared__ int pre[NPB];
    __shared__ int ms[SH];
    int b = blockIdx.x;
    int base = b * CAP;
    int t = threadIdx.x;
    if (t < NPB) cnt[t] = 0;
    if (t < SH) ms[t] = min(cursor[b * SH + t], CSUB);
    __syncthreads();

    int2 a[16];
    int  rk[16];
    bool vl[16];
#pragma unroll
    for (int r = 0; r < 16; ++r) {
        int seg = r >> 1;
        int p = ((r & 1) << 8) + t;          // (r&1)*256 + t
        vl[r] = p < ms[seg];
        if (vl[r]) {
            a[r] = adjB[base + seg * CSUB + p];
            rk[r] = atomicAdd(&cnt[((unsigned)a[r].x) >> 20], 1);
        }
    }
    __syncthreads();

    // wave-0 exclusive scan of cnt[128] -> pre (2 elems per lane, shfl scan)
    if (t < 64) {
        int c0 = cnt[2 * t], c1 = cnt[2 * t + 1];
        int s = c0 + c1;
        int incl = s;
#pragma unroll
        for (int d = 1; d < 64; d <<= 1) {
            int v = __shfl_up(incl, d, 64);
            if (t >= d) incl += v;
        }
        int excl = incl - s;
        pre[2 * t] = excl;
        pre[2 * t + 1] = excl + c0;
    }
    __syncthreads();

#pragma unroll
    for (int r = 0; r < 16; ++r) {
        if (vl[r]) {
            int dL = ((unsigned)a[r].x) >> 20;
            adj[base + pre[dL] + rk[r]] = make_int2(a[r].x & 0xFFFFF, a[r].y);
        }
    }
    if (t < NPB) {
        int node = b * NPB + t;
        if (node < N) {
            rowStart[node] = base + pre[t];
            rowEnd[node]   = base + pre[t] + cnt[t];
        }
    }
}

// ---------------------------------------------------------------------------
// Tiled row GEMM -> bf16 packed proj. Block = 64 rows; A transposed in LDS;
// theta in LDS; thread computes 4x4 block. __launch_bounds__(256,4) caps
// VGPR at 128 (r5: epilogue hoisting -> 252 VGPR, 9% occupancy).
// ---------------------------------------------------------------------------
__global__ __launch_bounds__(256, 4) void rowgemm_bf16_kernel(const float* __restrict__ A,
                                                              const float* __restrict__ theta,
                                                              unsigned short* __restrict__ proj16,
                                                              int N) {
    __shared__ float th[D * D];
    __shared__ float at[D][68];
    int t = threadIdx.x;
    int rowBase = blockIdx.x * 64;

#pragma unroll
    for (int i = 0; i < 4; ++i) {
        int f = t + i * 256;
        ((float4*)th)[f] = ((const float4*)theta)[f];
    }
#pragma unroll
    for (int i = 0; i < 4; ++i) {
        int f = t + i * 256;
        int row = f >> 4;
        int kv = f & 15;
        float4 v = make_float4(0.f, 0.f, 0.f, 0.f);
        if (rowBase + row < N) v = *(const float4*)&A[(size_t)(rowBase + row) * D + kv * 4];
        at[kv * 4 + 0][row] = v.x;
        at[kv * 4 + 1][row] = v.y;
        at[kv * 4 + 2][row] = v.z;
        at[kv * 4 + 3][row] = v.w;
    }
    __syncthreads();

    int c0 = (t & 15) * 4;
    int r0 = (t >> 4) * 4;
    float4 acc0 = make_float4(0.f, 0.f, 0.f, 0.f);
    float4 acc1 = acc0, acc2 = acc0, acc3 = acc0;

#pragma unroll 16
    for (int k = 0; k < D; ++k) {
        float4 bv = *(const float4*)&th[k * D + c0];
        float4 av = *(const float4*)&at[k][r0];
        acc0.x += av.x * bv.x; acc0.y += av.x * bv.y; acc0.z += av.x * bv.z; acc0.w += av.x * bv.w;
        acc1.x += av.y * bv.x; acc1.y += av.y * bv.y; acc1.z += av.y * bv.z; acc1.w += av.y * bv.w;
        acc2.x += av.z * bv.x; acc2.y += av.z * bv.y; acc2.z += av.z * bv.z; acc2.w += av.z * bv.w;
        acc3.x += av.w * bv.x; acc3.y += av.w * bv.y; acc3.z += av.w * bv.z; acc3.w += av.w * bv.w;
    }

    float4 accs[4] = {acc0, acc1, acc2, acc3};
#pragma unroll
    for (int i = 0; i < 4; ++i) {
        int r = rowBase + r0 + i;
        if (r < N) {
            unsigned lo = f2bf(accs[i].x) | (f2bf(accs[i].y) << 16);
            unsigned hi = f2bf(accs[i].z) | (f2bf(accs[i].w) << 16);
            *(uint2*)&proj16[(size_t)r * D + c0] = make_uint2(lo, hi);
        }
    }
}

// ---------------------------------------------------------------------------
// gather (proven r8/r9): one wave per node; each HALF-wave handles 4 edges
// per iteration via uniform-address adj loads; 4 independent 256B proj row
// loads in flight per wave. Tail: predicated weight=0.
// ---------------------------------------------------------------------------
__global__ void gather_kernel(const int* __restrict__ rowStart, const int* __restrict__ rowEnd,
                              const int2* __restrict__ adj,
                              const unsigned* __restrict__ projU, float* __restrict__ out, int N) {
    int wid = (blockIdx.x * blockDim.x + threadIdx.x) >> 6;
    int lane = threadIdx.x & 63;
    if (wid >= N) return;
    int beg = rowStart[wid];
    int end = rowEnd[wid];
    int half = lane >> 5;
    int k = lane & 31;

    float2 acc0 = make_float2(0.f, 0.f);
    float2 acc1 = acc0, acc2 = acc0, acc3 = acc0;

    for (int it = beg; it < end; it += 8) {
        int e0 = it + 0 + half;
        int e1 = it + 2 + half;
        int e2 = it + 4 + half;
        int e3 = it + 6 + half;
        int2 a0 = adj[e0 < end ? e0 : beg];
        int2 a1 = adj[e1 < end ? e1 : beg];
        int2 a2 = adj[e2 < end ? e2 : beg];
        int2 a3 = adj[e3 < end ? e3 : beg];
        float w0 = (e0 < end) ? __int_as_float(a0.y) : 0.f;
        float w1 = (e1 < end) ? __int_as_float(a1.y) : 0.f;
        float w2 = (e2 < end) ? __int_as_float(a2.y) : 0.f;
        float w3 = (e3 < end) ? __int_as_float(a3.y) : 0.f;
        unsigned p0 = projU[(size_t)a0.x * 32 + k];
        unsigned p1 = projU[(size_t)a1.x * 32 + k];
        unsigned p2 = projU[(size_t)a2.x * 32 + k];
        unsigned p3 = projU[(size_t)a3.x * 32 + k];
        acc0.x += w0 * __uint_as_float(p0 << 16);
        acc0.y += w0 * __uint_as_float(p0 & 0xFFFF0000u);
        acc1.x += w1 * __uint_as_float(p1 << 16);
        acc1.y += w1 * __uint_as_float(p1 & 0xFFFF0000u);
        acc2.x += w2 * __uint_as_float(p2 << 16);
        acc2.y += w2 * __uint_as_float(p2 & 0xFFFF0000u);
        acc3.x += w3 * __uint_as_float(p3 << 16);
        acc3.y += w3 * __uint_as_float(p3 & 0xFFFF0000u);
    }
    float2 acc = make_float2(acc0.x + acc1.x + acc2.x + acc3.x,
                             acc0.y + acc1.y + acc2.y + acc3.y);
    acc.x += __shfl(acc.x, lane ^ 32, 64);
    acc.y += __shfl(acc.y, lane ^ 32, 64);
    if (half == 0)
        *(float2*)&out[(size_t)wid * D + 2 * k] = acc;   // 32 lanes x 8B coalesced
}

// ---------------------------------------------------------------------------
// fallback path (atomic scatter + fp32 row GEMM) if ws/shape checks fail
// ---------------------------------------------------------------------------
__global__ void scatter_kernel(const int* __restrict__ src, const int* __restrict__ dst,
                               const float* __restrict__ w, const float* __restrict__ data,
                               float* __restrict__ agg, int E) {
    int tid = blockIdx.x * blockDim.x + threadIdx.x;
    int e = tid >> 6;
    int d = tid & 63;
    if (e >= E) return;
    float val = w[e] * data[(size_t)src[e] * D + d];
    atomicAdd(&agg[(size_t)dst[e] * D + d], val);
}

__global__ __launch_bounds__(256, 4) void rowgemm_f32_kernel(const float* __restrict__ A,
                                                             const float* __restrict__ theta,
                                                             float* __restrict__ out, int N) {
    __shared__ float th[D * D];
    __shared__ float at[D][68];
    int t = threadIdx.x;
    int rowBase = blockIdx.x * 64;
#pragma unroll
    for (int i = 0; i < 4; ++i) {
        int f = t + i * 256;
        ((float4*)th)[f] = ((const float4*)theta)[f];
    }
#pragma unroll
    for (int i = 0; i < 4; ++i) {
        int f = t + i * 256;
        int row = f >> 4;
        int kv = f & 15;
        float4 v = make_float4(0.f, 0.f, 0.f, 0.f);
        if (rowBase + row < N) v = *(const float4*)&A[(size_t)(rowBase + row) * D + kv * 4];
        at[kv * 4 + 0][row] = v.x;
        at[kv * 4 + 1][row] = v.y;
        at[kv * 4 + 2][row] = v.z;
        at[kv * 4 + 3][row] = v.w;
    }
    __syncthreads();
    int c0 = (t & 15) * 4;
    int r0 = (t >> 4) * 4;
    float4 acc0 = make_float4(0.f, 0.f, 0.f, 0.f);
    float4 acc1 = acc0, acc2 = acc0, acc3 = acc0;
#pragma unroll 16
    for (int kk = 0; kk < D; ++kk) {
        float4 bv = *(const float4*)&th[kk * D + c0];
        float4 av = *(const float4*)&at[kk][r0];
        acc0.x += av.x * bv.x; acc0.y += av.x * bv.y; acc0.z += av.x * bv.z; acc0.w += av.x * bv.w;
        acc1.x += av.y * bv.x; acc1.y += av.y * bv.y; acc1.z += av.y * bv.z; acc1.w += av.y * bv.w;
        acc2.x += av.z * bv.x; acc2.y += av.z * bv.y; acc2.z += av.z * bv.z; acc2.w += av.z * bv.w;
        acc3.x += av.w * bv.x; acc3.y += av.w * bv.y; acc3.z += av.w * bv.z; acc3.w += av.w * bv.w;
    }
    float4 accs[4] = {acc0, acc1, acc2, acc3};
#pragma unroll
    for (int i = 0; i < 4; ++i) {
        int r = rowBase + r0 + i;
        if (r < N) *(float4*)&out[(size_t)r * D + c0] = accs[i];
    }
}

extern "C" void kernel_launch(void* const* d_in, const int* in_sizes, int n_in,
                              void* d_out, int out_size, void* d_ws, size_t ws_size,
                              hipStream_t stream) {
    const int*   src   = (const int*)d_in[0];
    const int*   dst   = (const int*)d_in[1];
    const float* w     = (const float*)d_in[2];
    const float* data  = (const float*)d_in[3];
    const float* theta = (const float*)d_in[4];
    const int E = in_sizes[0];
    const int N = in_sizes[3] / D;
    float* out = (float*)d_out;

    const int B = (N + NPB - 1) / NPB;

    // ws layout: proj16 (bf16) | adjB (B*CAP slotted) | adj (B*CAP) |
    //            cursor[B*SH] | rowStart[N] | rowEnd[N]
    size_t projBytes = (size_t)N * D * 2;
    size_t slotBytes = (size_t)B * CAP * 8;
    size_t need = projBytes + 2 * slotBytes + (size_t)B * SH * 4 + (size_t)N * 8 + 256;

    // per-shard mean fill must sit far below CSUB
    long long meanFill = (B > 0) ? (long long)E / ((long long)B * SH) : 0;
    bool capOk = meanFill * 2 + 64 < CSUB;

    if (ws_size >= need && N < (1 << 20) && capOk) {
        unsigned short* proj16 = (unsigned short*)d_ws;
        int2* adjB     = (int2*)((char*)d_ws + projBytes);
        int2* adj      = (int2*)((char*)d_ws + projBytes + slotBytes);
        int*  cursor   = (int*)((char*)d_ws + projBytes + 2 * slotBytes);
        int*  rowStart = cursor + B * SH;
        int*  rowEnd   = rowStart + N;

        zero_i_kernel<<<(B * SH + 255) / 256, 256, 0, stream>>>(cursor, B * SH);
        fill_bucket_kernel<<<(E + 255) / 256, 256, 0, stream>>>(src, dst, w, cursor, adjB, E);
        sort_bucket_kernel<<<B, 256, 0, stream>>>(adjB, cursor, adj, rowStart, rowEnd, N);
        rowgemm_bf16_kernel<<<(N + 63) / 64, 256, 0, stream>>>(data, theta, proj16, N);
        gather_kernel<<<(N + 3) / 4, 256, 0, stream>>>(rowStart, rowEnd, adj,
                                                       (const unsigned*)proj16, out, N);
    } else {
        float* agg = (float*)d_ws;
        int n4 = (N * D) / 4;
        zero_f4_kernel<<<(n4 + 255) / 256, 256, 0, stream>>>((float4*)agg, n4);
        long long total = (long long)E * D;
        scatter_kernel<<<(int)((total + 255) / 256), 256, 0, stream>>>(src, dst, w, data, agg, E);
        rowgemm_f32_kernel<<<(N + 63) / 64, 256, 0, stream>>>(agg, theta, out, N);
    }
}